// Round 1
// baseline (1714.764 us; speedup 1.0000x reference)
//
#include <hip/hip_runtime.h>
#include <math.h>

#define B_ 4
#define HH 48
#define WW 48
#define LL 2304      // 48*48
#define CIN 192
#define COUT 96
#define DIN 192
#define NST 16
#define RNK 6
#define KDIR 4
#define HID 192

__device__ __forceinline__ float softplusf(float x) {
    return (x > 20.f) ? x : log1pf(expf(x));
}
__device__ __forceinline__ float siluf(float x) {
    return x / (1.f + expf(-x));
}
__device__ __forceinline__ float geluf(float x) {
    return 0.5f * x * (1.f + erff(x * 0.70710678118654752f));
}

// block-wide sum; nthreads multiple of 64; sbuf >= nthreads/64 floats
__device__ __forceinline__ float block_sum(float v, float* sbuf, int tid, int nthreads) {
    for (int o = 32; o > 0; o >>= 1) v += __shfl_down(v, o, 64);
    int wid = tid >> 6;
    if ((tid & 63) == 0) sbuf[wid] = v;
    __syncthreads();
    float s = 0.f;
    int nw = nthreads >> 6;
    if (tid == 0) {
        for (int i = 0; i < nw; i++) s += sbuf[i];
        sbuf[0] = s;
    }
    __syncthreads();
    s = sbuf[0];
    __syncthreads();
    return s;
}

// K1: x = x_cat@proj_W+b ; xn=LN(x) ; xz = xn@in_proj_W+b -> xmraw, z
__global__ __launch_bounds__(128) void k1_proj_ln_inproj(
    const float* __restrict__ xcat, const float* __restrict__ projW,
    const float* __restrict__ projb, const float* __restrict__ ln1w,
    const float* __restrict__ ln1b, const float* __restrict__ inW,
    const float* __restrict__ inb, float* __restrict__ x,
    float* __restrict__ xmraw, float* __restrict__ z) {
    int pos = blockIdx.x;  // b*LL + l
    int tid = threadIdx.x; // 128
    __shared__ float sxc[CIN];
    __shared__ float sxn[COUT];
    __shared__ float sred[2];
    const float* xr = xcat + (size_t)pos * CIN;
    for (int i = tid; i < CIN; i += 128) sxc[i] = xr[i];
    __syncthreads();
    float xv = 0.f;
    if (tid < COUT) {
        float acc = projb[tid];
        for (int i = 0; i < CIN; i++) acc += sxc[i] * projW[i * COUT + tid];
        xv = acc;
        x[(size_t)pos * COUT + tid] = acc;
    }
    float s1 = block_sum(tid < COUT ? xv : 0.f, sred, tid, 128);
    float mean = s1 / (float)COUT;
    float dv = (tid < COUT) ? (xv - mean) : 0.f;
    float s2 = block_sum(dv * dv, sred, tid, 128);
    float rs = rsqrtf(s2 / (float)COUT + 1e-5f);
    if (tid < COUT) sxn[tid] = (xv - mean) * rs * ln1w[tid] + ln1b[tid];
    __syncthreads();
    for (int k0 = tid; k0 < 2 * DIN; k0 += 128) {
        float acc = inb[k0];
        for (int j = 0; j < COUT; j++) acc += sxn[j] * inW[j * (2 * DIN) + k0];
        if (k0 < DIN) xmraw[(size_t)pos * DIN + k0] = acc;
        else          z[(size_t)pos * DIN + (k0 - DIN)] = acc;
    }
}

// K2: depthwise 3x3 SAME + bias + SiLU  (NHWC)
__global__ __launch_bounds__(192) void k2_dwconv_silu(
    const float* __restrict__ xmraw, const float* __restrict__ cw,
    const float* __restrict__ cb, float* __restrict__ xm) {
    int pos = blockIdx.x;
    int c = threadIdx.x; // 192
    int b = pos / LL;
    int l = pos % LL;
    int h = l / WW;
    int w = l % WW;
    float acc = cb[c];
    for (int kh = 0; kh < 3; kh++) {
        int hh = h + kh - 1;
        if (hh < 0 || hh >= HH) continue;
        for (int kw = 0; kw < 3; kw++) {
            int ww2 = w + kw - 1;
            if (ww2 < 0 || ww2 >= WW) continue;
            acc += xmraw[((size_t)(b * LL + hh * WW + ww2)) * DIN + c] * cw[c * 9 + kh * 3 + kw];
        }
    }
    xm[(size_t)pos * DIN + c] = siluf(acc);
}

// K3: x_dbl = einsum(xs, x_proj_W); delta = softplus(dts + dt_b); split Bs/Cs
// delta layout (b,k,l,d); Bs/Cs layout (b,k,l,n)
__global__ __launch_bounds__(64) void k3_xdbl(
    const float* __restrict__ xm, const float* __restrict__ xprojW,
    const float* __restrict__ dtW, const float* __restrict__ dtb,
    float* __restrict__ delta, float* __restrict__ Bsb, float* __restrict__ Csb) {
    int gid = blockIdx.x;          // b*KDIR*LL + k*LL + l
    int l = gid % LL;
    int k = (gid / LL) & 3;
    int b = gid / (LL * KDIR);
    int tid = threadIdx.x;         // 64
    int lk = (k & 2) ? (LL - 1 - l) : l;
    int lphys = (k & 1) ? ((lk % HH) * WW + (lk / HH)) : lk;
    __shared__ float sx[DIN];
    __shared__ float sdbl[RNK + 2 * NST];
    const float* xr = xm + ((size_t)b * LL + lphys) * DIN;
    for (int i = tid; i < DIN; i += 64) sx[i] = xr[i];
    __syncthreads();
    if (tid < RNK + 2 * NST) {
        const float* wr = xprojW + ((size_t)k * (RNK + 2 * NST) + tid) * DIN;
        float acc = 0.f;
        for (int d = 0; d < DIN; d++) acc += sx[d] * wr[d];
        sdbl[tid] = acc;
    }
    __syncthreads();
    size_t base = ((size_t)(b * KDIR + k) * LL + l);
    if (tid < NST) {
        Bsb[base * NST + tid] = sdbl[RNK + tid];
        Csb[base * NST + tid] = sdbl[RNK + NST + tid];
    }
    for (int d = tid; d < DIN; d += 64) {
        const float* wr = dtW + ((size_t)k * DIN + d) * RNK;
        float acc = dtb[k * DIN + d];
        for (int r = 0; r < RNK; r++) acc += sdbl[r] * wr[r];
        delta[base * DIN + d] = softplusf(acc);
    }
}

// K4: selective scan. 16 lanes per (b,k,d) scan; 4 scans per wave; 64-thread blocks.
// writes ys at PHYSICAL spatial index so all 4 directions align for the merge.
__global__ __launch_bounds__(64) void k4_scan(
    const float* __restrict__ xm, const float* __restrict__ delta,
    const float* __restrict__ Bsb, const float* __restrict__ Csb,
    const float* __restrict__ Alogs, const float* __restrict__ Ds,
    float* __restrict__ ysp) {
    int tid = threadIdx.x;
    int grp = blockIdx.x * 4 + (tid >> 4); // scan id, 0..3071
    int n = tid & 15;
    int d = grp % DIN;
    int k = (grp / DIN) & 3;
    int b = grp / (DIN * KDIR);
    float A = -expf(Alogs[((size_t)(k * DIN + d)) * NST + n]);
    float Dv = Ds[k * DIN + d];
    float h = 0.f;
    size_t dbase = ((size_t)(b * KDIR + k) * LL) * DIN + d;   // delta (b,k,l,d)
    size_t bcbase = ((size_t)(b * KDIR + k) * LL) * NST + n;  // Bs/Cs (b,k,l,n)
    const float* xmb = xm + (size_t)b * LL * DIN + d;
    size_t ybase = ((size_t)(b * KDIR + k) * LL) * DIN + d;   // ysp (b,k,lphys,d)
    for (int l = 0; l < LL; l++) {
        int lk = (k & 2) ? (LL - 1 - l) : l;
        int lphys = (k & 1) ? ((lk % HH) * WW + (lk / HH)) : lk;
        float dl = delta[dbase + (size_t)l * DIN];
        float u = xmb[(size_t)lphys * DIN];
        float Bn = Bsb[bcbase + (size_t)l * NST];
        float Cn = Csb[bcbase + (size_t)l * NST];
        h = expf(dl * A) * h + dl * u * Bn;
        float y = h * Cn;
        y += __shfl_xor(y, 1, 16);
        y += __shfl_xor(y, 2, 16);
        y += __shfl_xor(y, 4, 16);
        y += __shfl_xor(y, 8, 16);
        if (n == 0) ysp[ybase + (size_t)lphys * DIN] = y + u * Dv;
    }
}

// K5: merge 4 directions + LN(DIN) + gate silu(z) + out_proj + residual -> x2
__global__ __launch_bounds__(192) void k5_combine(
    const float* __restrict__ ysp, const float* __restrict__ z,
    const float* __restrict__ onw, const float* __restrict__ onb,
    const float* __restrict__ opW, const float* __restrict__ x,
    float* __restrict__ x2) {
    int pos = blockIdx.x;
    int tid = threadIdx.x; // 192
    int b = pos / LL;
    int l = pos % LL;
    __shared__ float sg[DIN];
    __shared__ float sred[3];
    size_t base = ((size_t)(b * KDIR) * LL + l) * DIN + tid;
    const size_t kstride = (size_t)LL * DIN;
    float y = ysp[base] + ysp[base + kstride] + ysp[base + 2 * kstride] + ysp[base + 3 * kstride];
    float s1 = block_sum(y, sred, tid, 192);
    float mean = s1 / (float)DIN;
    float dv = y - mean;
    float s2 = block_sum(dv * dv, sred, tid, 192);
    float rs = rsqrtf(s2 / (float)DIN + 1e-5f);
    float yn = (y - mean) * rs * onw[tid] + onb[tid];
    float zv = z[(size_t)pos * DIN + tid];
    sg[tid] = yn * siluf(zv);
    __syncthreads();
    if (tid < COUT) {
        float acc = 0.f;
        for (int dd = 0; dd < DIN; dd++) acc += sg[dd] * opW[dd * COUT + tid];
        x2[(size_t)pos * COUT + tid] = x[(size_t)pos * COUT + tid] + acc;
    }
}

// K6a: pw1 (96->192) + bn1 + gelu
__global__ __launch_bounds__(192) void k6a_pw1(
    const float* __restrict__ x2, const float* __restrict__ w1,
    const float* __restrict__ g1, const float* __restrict__ b1,
    float* __restrict__ t1) {
    int pos = blockIdx.x;
    int c = threadIdx.x; // 192
    __shared__ float sx[COUT];
    if (c < COUT) sx[c] = x2[(size_t)pos * COUT + c];
    __syncthreads();
    const float* wr = w1 + (size_t)c * COUT;
    float acc = 0.f;
    for (int j = 0; j < COUT; j++) acc += sx[j] * wr[j];
    acc = acc * g1[c] + b1[c];
    t1[(size_t)pos * HID + c] = geluf(acc);
}

// K6b: depthwise 3x3 SAME (no bias) + bn2 + gelu
__global__ __launch_bounds__(192) void k6b_dw(
    const float* __restrict__ t1, const float* __restrict__ cw,
    const float* __restrict__ g2, const float* __restrict__ b2,
    float* __restrict__ t2) {
    int pos = blockIdx.x;
    int c = threadIdx.x; // 192
    int b = pos / LL;
    int l = pos % LL;
    int h = l / WW;
    int w = l % WW;
    float acc = 0.f;
    for (int kh = 0; kh < 3; kh++) {
        int hh = h + kh - 1;
        if (hh < 0 || hh >= HH) continue;
        for (int kw = 0; kw < 3; kw++) {
            int ww2 = w + kw - 1;
            if (ww2 < 0 || ww2 >= WW) continue;
            acc += t1[((size_t)(b * LL + hh * WW + ww2)) * HID + c] * cw[c * 9 + kh * 3 + kw];
        }
    }
    float v = acc * g2[c] + b2[c];
    t2[(size_t)pos * HID + c] = geluf(v);
}

// K6c: pw2 (192->96) + bn3 + residual + final LN -> out
__global__ __launch_bounds__(128) void k6c_pw2_ln(
    const float* __restrict__ t2, const float* __restrict__ w2,
    const float* __restrict__ g3, const float* __restrict__ b3,
    const float* __restrict__ x2, const float* __restrict__ nw,
    const float* __restrict__ nb, float* __restrict__ out) {
    int pos = blockIdx.x;
    int tid = threadIdx.x; // 128
    __shared__ float st[HID];
    __shared__ float sred[2];
    for (int i = tid; i < HID; i += 128) st[i] = t2[(size_t)pos * HID + i];
    __syncthreads();
    float xv = 0.f;
    if (tid < COUT) {
        const float* wr = w2 + (size_t)tid * HID;
        float acc = 0.f;
        for (int c = 0; c < HID; c++) acc += st[c] * wr[c];
        xv = x2[(size_t)pos * COUT + tid] + acc * g3[tid] + b3[tid];
    }
    float s1 = block_sum(tid < COUT ? xv : 0.f, sred, tid, 128);
    float mean = s1 / (float)COUT;
    float dv = (tid < COUT) ? (xv - mean) : 0.f;
    float s2 = block_sum(dv * dv, sred, tid, 128);
    float rs = rsqrtf(s2 / (float)COUT + 1e-5f);
    if (tid < COUT) out[(size_t)pos * COUT + tid] = (xv - mean) * rs * nw[tid] + nb[tid];
}

extern "C" void kernel_launch(void* const* d_in, const int* in_sizes, int n_in,
                              void* d_out, int out_size, void* d_ws, size_t ws_size,
                              hipStream_t stream) {
    const float* x_cat   = (const float*)d_in[0];
    const float* proj_W  = (const float*)d_in[1];
    const float* proj_b  = (const float*)d_in[2];
    const float* ln1_w   = (const float*)d_in[3];
    const float* ln1_b   = (const float*)d_in[4];
    const float* in_W    = (const float*)d_in[5];
    const float* in_b    = (const float*)d_in[6];
    const float* conv_W  = (const float*)d_in[7];
    const float* conv_b  = (const float*)d_in[8];
    const float* xproj_W = (const float*)d_in[9];
    const float* dt_W    = (const float*)d_in[10];
    const float* dt_b    = (const float*)d_in[11];
    const float* A_logs  = (const float*)d_in[12];
    const float* Ds      = (const float*)d_in[13];
    const float* onorm_w = (const float*)d_in[14];
    const float* onorm_b = (const float*)d_in[15];
    const float* oproj_W = (const float*)d_in[16];
    const float* pw1_W   = (const float*)d_in[17];
    const float* bn1_g   = (const float*)d_in[18];
    const float* bn1_b   = (const float*)d_in[19];
    const float* dw_W    = (const float*)d_in[20];
    const float* bn2_g   = (const float*)d_in[21];
    const float* bn2_b   = (const float*)d_in[22];
    const float* pw2_W   = (const float*)d_in[23];
    const float* bn3_g   = (const float*)d_in[24];
    const float* bn3_b   = (const float*)d_in[25];
    const float* norm_w  = (const float*)d_in[26];
    const float* norm_b  = (const float*)d_in[27];
    float* out = (float*)d_out;

    float* ws = (float*)d_ws;
    const size_t nPos = (size_t)B_ * LL;           // 9216
    float* x     = ws;                              // 884736
    float* xmraw = x + nPos * COUT;                 // 1769472
    float* z     = xmraw + nPos * DIN;              // 1769472
    float* xm    = z + nPos * DIN;                  // 1769472
    float* delta = xm + nPos * DIN;                 // 7077888
    float* Bsb   = delta + nPos * KDIR * DIN;       // 589824
    float* Csb   = Bsb + nPos * KDIR * NST;         // 589824
    float* ysp   = Csb + nPos * KDIR * NST;         // 7077888
    float* x2    = ysp + nPos * KDIR * DIN;         // 884736
    float* t1    = xmraw;  // reuse (dead after K2)
    float* t2    = z;      // reuse (dead after K5)

    hipLaunchKernelGGL(k1_proj_ln_inproj, dim3(nPos), dim3(128), 0, stream,
                       x_cat, proj_W, proj_b, ln1_w, ln1_b, in_W, in_b, x, xmraw, z);
    hipLaunchKernelGGL(k2_dwconv_silu, dim3(nPos), dim3(192), 0, stream,
                       xmraw, conv_W, conv_b, xm);
    hipLaunchKernelGGL(k3_xdbl, dim3(nPos * KDIR), dim3(64), 0, stream,
                       xm, xproj_W, dt_W, dt_b, delta, Bsb, Csb);
    hipLaunchKernelGGL(k4_scan, dim3((B_ * KDIR * DIN) / 4), dim3(64), 0, stream,
                       xm, delta, Bsb, Csb, A_logs, Ds, ysp);
    hipLaunchKernelGGL(k5_combine, dim3(nPos), dim3(192), 0, stream,
                       ysp, z, onorm_w, onorm_b, oproj_W, x, x2);
    hipLaunchKernelGGL(k6a_pw1, dim3(nPos), dim3(192), 0, stream,
                       x2, pw1_W, bn1_g, bn1_b, t1);
    hipLaunchKernelGGL(k6b_dw, dim3(nPos), dim3(192), 0, stream,
                       t1, dw_W, bn2_g, bn2_b, t2);
    hipLaunchKernelGGL(k6c_pw2_ln, dim3(nPos), dim3(128), 0, stream,
                       t2, pw2_W, bn3_g, bn3_b, x2, norm_w, norm_b, out);
}

// Round 2
// 869.689 us; speedup vs baseline: 1.9717x; 1.9717x over previous
//
#include <hip/hip_runtime.h>
#include <math.h>

#define B_ 4
#define HH 48
#define WW 48
#define LL 2304      // 48*48
#define CIN 192
#define COUT 96
#define DIN 192
#define NST 16
#define RNK 6
#define KDIR 4
#define HID 192

#define NCH 16       // scan chunks per sequence
#define CLEN (LL / NCH)  // 144

__device__ __forceinline__ float softplusf(float x) {
    return (x > 20.f) ? x : log1pf(expf(x));
}
__device__ __forceinline__ float siluf(float x) {
    return x / (1.f + expf(-x));
}
__device__ __forceinline__ float geluf(float x) {
    return 0.5f * x * (1.f + erff(x * 0.70710678118654752f));
}

// block-wide sum; nthreads multiple of 64; sbuf >= nthreads/64 floats
__device__ __forceinline__ float block_sum(float v, float* sbuf, int tid, int nthreads) {
    for (int o = 32; o > 0; o >>= 1) v += __shfl_down(v, o, 64);
    int wid = tid >> 6;
    if ((tid & 63) == 0) sbuf[wid] = v;
    __syncthreads();
    float s = 0.f;
    int nw = nthreads >> 6;
    if (tid == 0) {
        for (int i = 0; i < nw; i++) s += sbuf[i];
        sbuf[0] = s;
    }
    __syncthreads();
    s = sbuf[0];
    __syncthreads();
    return s;
}

// K1: x = x_cat@proj_W+b ; xn=LN(x) ; xz = xn@in_proj_W+b -> xmraw, z
__global__ __launch_bounds__(128) void k1_proj_ln_inproj(
    const float* __restrict__ xcat, const float* __restrict__ projW,
    const float* __restrict__ projb, const float* __restrict__ ln1w,
    const float* __restrict__ ln1b, const float* __restrict__ inW,
    const float* __restrict__ inb, float* __restrict__ x,
    float* __restrict__ xmraw, float* __restrict__ z) {
    int pos = blockIdx.x;  // b*LL + l
    int tid = threadIdx.x; // 128
    __shared__ float sxc[CIN];
    __shared__ float sxn[COUT];
    __shared__ float sred[2];
    const float* xr = xcat + (size_t)pos * CIN;
    for (int i = tid; i < CIN; i += 128) sxc[i] = xr[i];
    __syncthreads();
    float xv = 0.f;
    if (tid < COUT) {
        float acc = projb[tid];
        for (int i = 0; i < CIN; i++) acc += sxc[i] * projW[i * COUT + tid];
        xv = acc;
        x[(size_t)pos * COUT + tid] = acc;
    }
    float s1 = block_sum(tid < COUT ? xv : 0.f, sred, tid, 128);
    float mean = s1 / (float)COUT;
    float dv = (tid < COUT) ? (xv - mean) : 0.f;
    float s2 = block_sum(dv * dv, sred, tid, 128);
    float rs = rsqrtf(s2 / (float)COUT + 1e-5f);
    if (tid < COUT) sxn[tid] = (xv - mean) * rs * ln1w[tid] + ln1b[tid];
    __syncthreads();
    for (int k0 = tid; k0 < 2 * DIN; k0 += 128) {
        float acc = inb[k0];
        for (int j = 0; j < COUT; j++) acc += sxn[j] * inW[j * (2 * DIN) + k0];
        if (k0 < DIN) xmraw[(size_t)pos * DIN + k0] = acc;
        else          z[(size_t)pos * DIN + (k0 - DIN)] = acc;
    }
}

// K2: depthwise 3x3 SAME + bias + SiLU  (NHWC)
__global__ __launch_bounds__(192) void k2_dwconv_silu(
    const float* __restrict__ xmraw, const float* __restrict__ cw,
    const float* __restrict__ cb, float* __restrict__ xm) {
    int pos = blockIdx.x;
    int c = threadIdx.x; // 192
    int b = pos / LL;
    int l = pos % LL;
    int h = l / WW;
    int w = l % WW;
    float acc = cb[c];
    for (int kh = 0; kh < 3; kh++) {
        int hh = h + kh - 1;
        if (hh < 0 || hh >= HH) continue;
        for (int kw = 0; kw < 3; kw++) {
            int ww2 = w + kw - 1;
            if (ww2 < 0 || ww2 >= WW) continue;
            acc += xmraw[((size_t)(b * LL + hh * WW + ww2)) * DIN + c] * cw[c * 9 + kh * 3 + kw];
        }
    }
    xm[(size_t)pos * DIN + c] = siluf(acc);
}

// K3: x_dbl = einsum(xs, x_proj_W); delta = softplus(dts + dt_b); split Bs/Cs
// delta layout (b,k,l,d); Bs/Cs layout (b,k,l,n)
__global__ __launch_bounds__(64) void k3_xdbl(
    const float* __restrict__ xm, const float* __restrict__ xprojW,
    const float* __restrict__ dtW, const float* __restrict__ dtb,
    float* __restrict__ delta, float* __restrict__ Bsb, float* __restrict__ Csb) {
    int gid = blockIdx.x;          // b*KDIR*LL + k*LL + l
    int l = gid % LL;
    int k = (gid / LL) & 3;
    int b = gid / (LL * KDIR);
    int tid = threadIdx.x;         // 64
    int lk = (k & 2) ? (LL - 1 - l) : l;
    int lphys = (k & 1) ? ((lk % HH) * WW + (lk / HH)) : lk;
    __shared__ float sx[DIN];
    __shared__ float sdbl[RNK + 2 * NST];
    const float* xr = xm + ((size_t)b * LL + lphys) * DIN;
    for (int i = tid; i < DIN; i += 64) sx[i] = xr[i];
    __syncthreads();
    if (tid < RNK + 2 * NST) {
        const float* wr = xprojW + ((size_t)k * (RNK + 2 * NST) + tid) * DIN;
        float acc = 0.f;
        for (int d = 0; d < DIN; d++) acc += sx[d] * wr[d];
        sdbl[tid] = acc;
    }
    __syncthreads();
    size_t base = ((size_t)(b * KDIR + k) * LL + l);
    if (tid < NST) {
        Bsb[base * NST + tid] = sdbl[RNK + tid];
        Csb[base * NST + tid] = sdbl[RNK + NST + tid];
    }
    for (int d = tid; d < DIN; d += 64) {
        const float* wr = dtW + ((size_t)k * DIN + d) * RNK;
        float acc = dtb[k * DIN + d];
        for (int r = 0; r < RNK; r++) acc += sdbl[r] * wr[r];
        delta[base * DIN + d] = softplusf(acc);
    }
}

// K4 v2: chunk-parallel selective scan.
// One block of 256 threads per (b,k,d) scan: thread = (chunk c = tid>>4, state n = tid&15).
// Pass A: per-chunk (P = exp(A*sum_dl), Q = chunk output with h0=0).
// LDS combine: serial over 16 chunks to get each chunk's true start state.
// Pass B: rerun chunk from true start, y = sum_n h*C, write at PHYSICAL index.
__global__ __launch_bounds__(256) void k4_scan(
    const float* __restrict__ xm, const float* __restrict__ delta,
    const float* __restrict__ Bsb, const float* __restrict__ Csb,
    const float* __restrict__ Alogs, const float* __restrict__ Ds,
    float* __restrict__ ysp) {
    int tid = threadIdx.x;
    int c = tid >> 4;      // chunk 0..15
    int n = tid & 15;      // state 0..15
    int d = blockIdx.x % DIN;
    int k = (blockIdx.x / DIN) & 3;
    int b = blockIdx.x / (DIN * KDIR);

    __shared__ float sP[NCH * NST];
    __shared__ float sQ[NCH * NST];
    __shared__ float sH[NCH * NST];

    float A = -expf(Alogs[((size_t)(k * DIN + d)) * NST + n]);
    float Dv = Ds[k * DIN + d];

    size_t dbase = ((size_t)(b * KDIR + k) * LL) * DIN + d;   // delta (b,k,l,d)
    size_t bcbase = ((size_t)(b * KDIR + k) * LL) * NST + n;  // Bs/Cs (b,k,l,n)
    const float* xmb = xm + (size_t)b * LL * DIN + d;
    size_t ybase = ((size_t)(b * KDIR + k) * LL) * DIN + d;   // ysp (b,k,lphys,d)

    const int l0 = c * CLEN;

    // ---- Pass A: chunk-local scan with h0 = 0 ----
    float Q = 0.f;
    float sum_dl = 0.f;
    #pragma unroll 4
    for (int i = 0; i < CLEN; i++) {
        int l = l0 + i;
        int lk = (k & 2) ? (LL - 1 - l) : l;
        int lphys = (k & 1) ? ((lk % HH) * WW + (lk / HH)) : lk;
        float dl = delta[dbase + (size_t)l * DIN];
        float u = xmb[(size_t)lphys * DIN];
        float Bn = Bsb[bcbase + (size_t)l * NST];
        sum_dl += dl;
        Q = expf(dl * A) * Q + dl * u * Bn;
    }
    sP[c * NST + n] = expf(A * sum_dl);
    sQ[c * NST + n] = Q;
    __syncthreads();

    // ---- Combine: serial prefix over chunks (16 threads, one per n) ----
    if (tid < NST) {
        float h = 0.f;
        sH[tid] = 0.f;
        for (int cc = 1; cc < NCH; cc++) {
            h = sP[(cc - 1) * NST + tid] * h + sQ[(cc - 1) * NST + tid];
            sH[cc * NST + tid] = h;
        }
    }
    __syncthreads();

    // ---- Pass B: rerun chunk from true start state, emit y ----
    float h = sH[c * NST + n];
    #pragma unroll 4
    for (int i = 0; i < CLEN; i++) {
        int l = l0 + i;
        int lk = (k & 2) ? (LL - 1 - l) : l;
        int lphys = (k & 1) ? ((lk % HH) * WW + (lk / HH)) : lk;
        float dl = delta[dbase + (size_t)l * DIN];
        float u = xmb[(size_t)lphys * DIN];
        float Bn = Bsb[bcbase + (size_t)l * NST];
        float Cn = Csb[bcbase + (size_t)l * NST];
        h = expf(dl * A) * h + dl * u * Bn;
        float y = h * Cn;
        y += __shfl_xor(y, 1, 16);
        y += __shfl_xor(y, 2, 16);
        y += __shfl_xor(y, 4, 16);
        y += __shfl_xor(y, 8, 16);
        if (n == 0) ysp[ybase + (size_t)lphys * DIN] = y + u * Dv;
    }
}

// K5: merge 4 directions + LN(DIN) + gate silu(z) + out_proj + residual -> x2
__global__ __launch_bounds__(192) void k5_combine(
    const float* __restrict__ ysp, const float* __restrict__ z,
    const float* __restrict__ onw, const float* __restrict__ onb,
    const float* __restrict__ opW, const float* __restrict__ x,
    float* __restrict__ x2) {
    int pos = blockIdx.x;
    int tid = threadIdx.x; // 192
    int b = pos / LL;
    int l = pos % LL;
    __shared__ float sg[DIN];
    __shared__ float sred[3];
    size_t base = ((size_t)(b * KDIR) * LL + l) * DIN + tid;
    const size_t kstride = (size_t)LL * DIN;
    float y = ysp[base] + ysp[base + kstride] + ysp[base + 2 * kstride] + ysp[base + 3 * kstride];
    float s1 = block_sum(y, sred, tid, 192);
    float mean = s1 / (float)DIN;
    float dv = y - mean;
    float s2 = block_sum(dv * dv, sred, tid, 192);
    float rs = rsqrtf(s2 / (float)DIN + 1e-5f);
    float yn = (y - mean) * rs * onw[tid] + onb[tid];
    float zv = z[(size_t)pos * DIN + tid];
    sg[tid] = yn * siluf(zv);
    __syncthreads();
    if (tid < COUT) {
        float acc = 0.f;
        for (int dd = 0; dd < DIN; dd++) acc += sg[dd] * opW[dd * COUT + tid];
        x2[(size_t)pos * COUT + tid] = x[(size_t)pos * COUT + tid] + acc;
    }
}

// K6a: pw1 (96->192) + bn1 + gelu
__global__ __launch_bounds__(192) void k6a_pw1(
    const float* __restrict__ x2, const float* __restrict__ w1,
    const float* __restrict__ g1, const float* __restrict__ b1,
    float* __restrict__ t1) {
    int pos = blockIdx.x;
    int c = threadIdx.x; // 192
    __shared__ float sx[COUT];
    if (c < COUT) sx[c] = x2[(size_t)pos * COUT + c];
    __syncthreads();
    const float* wr = w1 + (size_t)c * COUT;
    float acc = 0.f;
    for (int j = 0; j < COUT; j++) acc += sx[j] * wr[j];
    acc = acc * g1[c] + b1[c];
    t1[(size_t)pos * HID + c] = geluf(acc);
}

// K6b: depthwise 3x3 SAME (no bias) + bn2 + gelu
__global__ __launch_bounds__(192) void k6b_dw(
    const float* __restrict__ t1, const float* __restrict__ cw,
    const float* __restrict__ g2, const float* __restrict__ b2,
    float* __restrict__ t2) {
    int pos = blockIdx.x;
    int c = threadIdx.x; // 192
    int b = pos / LL;
    int l = pos % LL;
    int h = l / WW;
    int w = l % WW;
    float acc = 0.f;
    for (int kh = 0; kh < 3; kh++) {
        int hh = h + kh - 1;
        if (hh < 0 || hh >= HH) continue;
        for (int kw = 0; kw < 3; kw++) {
            int ww2 = w + kw - 1;
            if (ww2 < 0 || ww2 >= WW) continue;
            acc += t1[((size_t)(b * LL + hh * WW + ww2)) * HID + c] * cw[c * 9 + kh * 3 + kw];
        }
    }
    float v = acc * g2[c] + b2[c];
    t2[(size_t)pos * HID + c] = geluf(v);
}

// K6c: pw2 (192->96) + bn3 + residual + final LN -> out
__global__ __launch_bounds__(128) void k6c_pw2_ln(
    const float* __restrict__ t2, const float* __restrict__ w2,
    const float* __restrict__ g3, const float* __restrict__ b3,
    const float* __restrict__ x2, const float* __restrict__ nw,
    const float* __restrict__ nb, float* __restrict__ out) {
    int pos = blockIdx.x;
    int tid = threadIdx.x; // 128
    __shared__ float st[HID];
    __shared__ float sred[2];
    for (int i = tid; i < HID; i += 128) st[i] = t2[(size_t)pos * HID + i];
    __syncthreads();
    float xv = 0.f;
    if (tid < COUT) {
        const float* wr = w2 + (size_t)tid * HID;
        float acc = 0.f;
        for (int c = 0; c < HID; c++) acc += st[c] * wr[c];
        xv = x2[(size_t)pos * COUT + tid] + acc * g3[tid] + b3[tid];
    }
    float s1 = block_sum(tid < COUT ? xv : 0.f, sred, tid, 128);
    float mean = s1 / (float)COUT;
    float dv = (tid < COUT) ? (xv - mean) : 0.f;
    float s2 = block_sum(dv * dv, sred, tid, 128);
    float rs = rsqrtf(s2 / (float)COUT + 1e-5f);
    if (tid < COUT) out[(size_t)pos * COUT + tid] = (xv - mean) * rs * nw[tid] + nb[tid];
}

extern "C" void kernel_launch(void* const* d_in, const int* in_sizes, int n_in,
                              void* d_out, int out_size, void* d_ws, size_t ws_size,
                              hipStream_t stream) {
    const float* x_cat   = (const float*)d_in[0];
    const float* proj_W  = (const float*)d_in[1];
    const float* proj_b  = (const float*)d_in[2];
    const float* ln1_w   = (const float*)d_in[3];
    const float* ln1_b   = (const float*)d_in[4];
    const float* in_W    = (const float*)d_in[5];
    const float* in_b    = (const float*)d_in[6];
    const float* conv_W  = (const float*)d_in[7];
    const float* conv_b  = (const float*)d_in[8];
    const float* xproj_W = (const float*)d_in[9];
    const float* dt_W    = (const float*)d_in[10];
    const float* dt_b    = (const float*)d_in[11];
    const float* A_logs  = (const float*)d_in[12];
    const float* Ds      = (const float*)d_in[13];
    const float* onorm_w = (const float*)d_in[14];
    const float* onorm_b = (const float*)d_in[15];
    const float* oproj_W = (const float*)d_in[16];
    const float* pw1_W   = (const float*)d_in[17];
    const float* bn1_g   = (const float*)d_in[18];
    const float* bn1_b   = (const float*)d_in[19];
    const float* dw_W    = (const float*)d_in[20];
    const float* bn2_g   = (const float*)d_in[21];
    const float* bn2_b   = (const float*)d_in[22];
    const float* pw2_W   = (const float*)d_in[23];
    const float* bn3_g   = (const float*)d_in[24];
    const float* bn3_b   = (const float*)d_in[25];
    const float* norm_w  = (const float*)d_in[26];
    const float* norm_b  = (const float*)d_in[27];
    float* out = (float*)d_out;

    float* ws = (float*)d_ws;
    const size_t nPos = (size_t)B_ * LL;           // 9216
    float* x     = ws;                              // 884736
    float* xmraw = x + nPos * COUT;                 // 1769472
    float* z     = xmraw + nPos * DIN;              // 1769472
    float* xm    = z + nPos * DIN;                  // 1769472
    float* delta = xm + nPos * DIN;                 // 7077888
    float* Bsb   = delta + nPos * KDIR * DIN;       // 589824
    float* Csb   = Bsb + nPos * KDIR * NST;         // 589824
    float* ysp   = Csb + nPos * KDIR * NST;         // 7077888
    float* x2    = ysp + nPos * KDIR * DIN;         // 884736
    float* t1    = xmraw;  // reuse (dead after K2)
    float* t2    = z;      // reuse (dead after K5)

    hipLaunchKernelGGL(k1_proj_ln_inproj, dim3(nPos), dim3(128), 0, stream,
                       x_cat, proj_W, proj_b, ln1_w, ln1_b, in_W, in_b, x, xmraw, z);
    hipLaunchKernelGGL(k2_dwconv_silu, dim3(nPos), dim3(192), 0, stream,
                       xmraw, conv_W, conv_b, xm);
    hipLaunchKernelGGL(k3_xdbl, dim3(nPos * KDIR), dim3(64), 0, stream,
                       xm, xproj_W, dt_W, dt_b, delta, Bsb, Csb);
    hipLaunchKernelGGL(k4_scan, dim3(B_ * KDIR * DIN), dim3(256), 0, stream,
                       xm, delta, Bsb, Csb, A_logs, Ds, ysp);
    hipLaunchKernelGGL(k5_combine, dim3(nPos), dim3(192), 0, stream,
                       ysp, z, onorm_w, onorm_b, oproj_W, x, x2);
    hipLaunchKernelGGL(k6a_pw1, dim3(nPos), dim3(192), 0, stream,
                       x2, pw1_W, bn1_g, bn1_b, t1);
    hipLaunchKernelGGL(k6b_dw, dim3(nPos), dim3(192), 0, stream,
                       t1, dw_W, bn2_g, bn2_b, t2);
    hipLaunchKernelGGL(k6c_pw2_ln, dim3(nPos), dim3(128), 0, stream,
                       t2, pw2_W, bn3_g, bn3_b, x2, norm_w, norm_b, out);
}